// Round 1
// baseline (272.296 us; speedup 1.0000x reference)
//
#include <hip/hip_runtime.h>
#include <stdint.h>

typedef unsigned short u16;
typedef unsigned int   u32;

#define Bn 4
#define Cc 512
#define Hh 96
#define Ww 96
#define HWc (Hh*Ww)   // 9216
#define AH 11
#define Rr 512
#define CP (Cc/2)     // 256 dwords per point (bf16 NHWC)

__device__ __forceinline__ u16 f2bf(float f){
  u32 u = __float_as_uint(f);
  u += 0x7fffu + ((u>>16)&1u);
  return (u16)(u>>16);
}
__device__ __forceinline__ u32 pk2(float a, float b){
  return (u32)f2bf(a) | ((u32)f2bf(b)<<16);
}

// ---- fp32 NCHW -> bf16-pair (u32) NHWC transpose; 128hw x 128c tile ----
// LDS: u32 tile[128*64], XOR-swizzled col' = cp ^ (hw>>2)  -> conflict-free
__global__ __launch_bounds__(256)
void transpose_kernel(const float* __restrict__ in, u32* __restrict__ out){
  __shared__ u32 tile[128*64];   // 32 KB
  const int t = threadIdx.x;
  const int hw0 = blockIdx.x*128, c0 = blockIdx.y*128, b = blockIdx.z;
  {
    const int q = t & 31, cp0 = t >> 5;           // q: hw quad, cp0: 0..7
    const float* ib = in + ((size_t)(b*Cc + c0))*HWc + hw0 + 4*q;
    #pragma unroll
    for (int p=0;p<8;++p){
      const int cp = cp0 + p*8;                   // 0..63 channel pair in tile
      const float* pa = ib + (size_t)(2*cp)*HWc;
      float4 A = *(const float4*)pa;
      float4 B = *(const float4*)(pa + HWc);
      const int cs = cp ^ q;                      // (4q+i)>>2 == q for i<4
      tile[(4*q+0)*64 + cs] = pk2(A.x,B.x);
      tile[(4*q+1)*64 + cs] = pk2(A.y,B.y);
      tile[(4*q+2)*64 + cs] = pk2(A.z,B.z);
      tile[(4*q+3)*64 + cs] = pk2(A.w,B.w);
    }
  }
  __syncthreads();
  {
    const int l = t & 63, wv = t >> 6;            // lane = cp, wave = row group
    u32* ob = out + ((size_t)b*HWc + hw0)*CP + (c0>>1) + l;
    #pragma unroll
    for (int k=0;k<32;++k){
      const int hw = wv*32 + k;
      ob[(size_t)hw*CP] = tile[hw*64 + (l ^ (hw>>2))];  // 256B contiguous store
    }
  }
}

// ---- fused RoIAlignAda + 3x3/s2 maxpool, NHWC bf16 ----
// grid 1024: r = bid>>1, half = bid&1; 256 threads (4 waves):
//   sub0 (t<128): ph rows 0..5, emits oy0,oy1, deposits max(rm4,rm5) in LDS
//   sub1 (t>=128): ph rows 6..10, emits oy3,oy4, then oy2 = max(part, rm6)
// doubles waves/CU (8 -> 16) with zero redundant row compute.
__global__ __launch_bounds__(256, 4)
void roi_align_max_nhwc(const u32* __restrict__ feat,
                        const float* __restrict__ rois,
                        float* __restrict__ out)
{
  __shared__ __align__(16) int4   s_ro[AH];
  __shared__ __align__(16) float4 s_rw[AH];
  __shared__ __align__(16) int4   s_co[AH];
  __shared__ __align__(16) float4 s_cw[AH];
  __shared__ int s_b;
  __shared__ __align__(16) float2 s_part[128][5];   // 5 KB: max(rm4,rm5)
  __shared__ __align__(16) float s_out[256*25];     // 25.6 KB

  const int t    = threadIdx.x;
  const int sub  = t >> 7;          // 0: rows 0..5, 1: rows 6..10
  const int tl   = t & 127;         // dword lane within half
  const int r    = blockIdx.x >> 1;
  const int half = blockIdx.x & 1;

  if (t == 0){
    int b = (int)rois[r*5+0];
    s_b = min(max(b, 0), Bn-1);
  }

  // geometry: threads 0..10 -> rows (ph), threads 64..74 -> cols (pw)
  if (t < AH || (t >= 64 && t < 64+AH)){
    const bool isrow = (t < AH);
    const int  p = isrow ? t : t-64;
    const float* rp = rois + r*5;
    const float c1 = rp[isrow?2:1], c2 = rp[isrow?4:3];
    // replicate np float32 ops exactly (no fp contraction at validity boundaries)
    float lo  = __fmul_rn(c1, 0.125f);
    float hi  = __fmul_rn(c2, 0.125f);
    float ext = fmaxf(__fsub_rn(hi,lo), 0.0f);
    float bin = __fdiv_rn(ext, 10.0f);
    float ctr = __fadd_rn(lo, __fmul_rn((float)p, bin));
    float strd = fmaxf(1.0f, rintf(__fdiv_rn(bin, 3.0f)));   // half-even == jnp.round
    bool ok = (ctr >= 0.0f) && (ctr < 96.0f);
    int rws[6]; float wts[6]; int nv=0;
    #pragma unroll
    for (int s=0;s<3;++s){
      float cc = __fadd_rn(ctr, __fmul_rn((float)(s-1), strd));
      bool vv = (cc >= 0.0f) && (cc < 96.0f);
      float fl = fminf(fmaxf(floorf(cc),0.0f),94.0f);
      float fr = __fsub_rn(cc, fl);
      int ri = (int)fl;
      rws[2*s]=ri; rws[2*s+1]=ri+1;
      wts[2*s]  = vv ? __fsub_rn(1.0f,fr) : 0.0f;
      wts[2*s+1]= vv ? fr : 0.0f;
      nv += vv?1:0;
    }
    float sc = ok ? (1.0f/(float)nv) : 0.0f;   // folds center_ok + 1/cnt (separable)
    // dedupe-merge (stride==1 here => <=4 unique), pad to 4 with w=0
    int cr[4]={0,0,0,0}; float cwv[4]={0.0f,0.0f,0.0f,0.0f}; int n=0;
    for (int k=0;k<6;++k){
      float wk=wts[k]; if (wk==0.0f) continue;
      int rr=rws[k]; bool fnd=false;
      for (int j=0;j<n;++j) if (cr[j]==rr){ cwv[j]+=wk; fnd=true; break; }
      if (!fnd && n<4){ cr[n]=rr; cwv[n]=wk; ++n; }
    }
    const int mul = isrow ? (Ww*CP) : CP;      // offsets in dwords
    if (isrow){
      s_ro[p] = make_int4(cr[0]*mul, cr[1]*mul, cr[2]*mul, cr[3]*mul);
      s_rw[p] = make_float4(cwv[0]*sc, cwv[1]*sc, cwv[2]*sc, cwv[3]*sc);
    } else {
      s_co[p] = make_int4(cr[0]*mul, cr[1]*mul, cr[2]*mul, cr[3]*mul);
      s_cw[p] = make_float4(cwv[0]*sc, cwv[1]*sc, cwv[2]*sc, cwv[3]*sc);
    }
  }
  __syncthreads();

  const u32* fbase = feat + (size_t)s_b*((size_t)HWc*CP);
  const int tb = half*128 + tl;                // this thread's dword lane

  // hoist column voffsets (BYTE offsets: bare saddr+voffset loads) + weights
  int   vo[AH][4]; float cwr[AH][4];
  #pragma unroll
  for (int pw=0; pw<AH; ++pw){
    int4 c4 = s_co[pw]; float4 w4 = s_cw[pw];
    vo[pw][0]=(tb+c4.x)*4; vo[pw][1]=(tb+c4.y)*4; vo[pw][2]=(tb+c4.z)*4; vo[pw][3]=(tb+c4.w)*4;
    cwr[pw][0]=w4.x; cwr[pw][1]=w4.y; cwr[pw][2]=w4.z; cwr[pw][3]=w4.w;
  }

  float2 awin[5], rm6s[5];
  const int ph0 = sub ? 6 : 0;
  const int phN = sub ? 10 : 5;
  #pragma unroll 1
  for (int ph=ph0; ph<=phN; ++ph){
    int4   r4 = s_ro[ph];
    float4 w4 = s_rw[ph];
    // scalar row bases (SGPR-pair addressing for the gathers)
    const char* r0 = (const char*)(fbase + __builtin_amdgcn_readfirstlane(r4.x));
    const char* r1 = (const char*)(fbase + __builtin_amdgcn_readfirstlane(r4.y));
    const char* r2 = (const char*)(fbase + __builtin_amdgcn_readfirstlane(r4.z));
    const char* r3 = (const char*)(fbase + __builtin_amdgcn_readfirstlane(r4.w));
    const float rw_[4] = {w4.x, w4.y, w4.z, w4.w};
    float2 binr[AH];
    #pragma unroll
    for (int pw=0; pw<AH; ++pw){
      u32 v[16];
      #pragma unroll
      for (int j=0;j<4;++j){
        v[0*4+j] = *(const u32*)(r0 + vo[pw][j]);
        v[1*4+j] = *(const u32*)(r1 + vo[pw][j]);
        v[2*4+j] = *(const u32*)(r2 + vo[pw][j]);
        v[3*4+j] = *(const u32*)(r3 + vo[pw][j]);
      }
      // separable: column-combine per row, then row-combine (no weight muls)
      float ax=0.0f, ay=0.0f;
      #pragma unroll
      for (int i=0;i<4;++i){
        float cx=0.0f, cy=0.0f;
        #pragma unroll
        for (int j=0;j<4;++j){
          u32 d = v[i*4+j];
          cx = fmaf(cwr[pw][j], __uint_as_float(d<<16),           cx);
          cy = fmaf(cwr[pw][j], __uint_as_float(d & 0xffff0000u), cy);
        }
        ax = fmaf(rw_[i], cx, ax);
        ay = fmaf(rw_[i], cy, ay);
      }
      binr[pw] = make_float2(ax, ay);
    }
    float2 rm[5];
    #pragma unroll
    for (int ox=0; ox<5; ++ox){
      rm[ox].x = fmaxf(fmaxf(binr[2*ox].x, binr[2*ox+1].x), binr[2*ox+2].x);
      rm[ox].y = fmaxf(fmaxf(binr[2*ox].y, binr[2*ox+1].y), binr[2*ox+2].y);
    }
    if (ph == ph0){
      #pragma unroll
      for (int ox=0; ox<5; ++ox){
        awin[ox] = rm[ox];
        if (sub) rm6s[ox] = rm[ox];    // keep rm6 for the straddling oy2 window
      }
    } else if (ph & 1){
      #pragma unroll
      for (int ox=0; ox<5; ++ox){
        awin[ox].x = fmaxf(awin[ox].x, rm[ox].x);
        awin[ox].y = fmaxf(awin[ox].y, rm[ox].y);
      }
    } else {
      const int oy = (ph-2) >> 1;      // sub0: 0,1   sub1: 3,4
      #pragma unroll
      for (int ox=0; ox<5; ++ox){
        s_out[(2*tl  )*25 + oy*5 + ox] = fmaxf(awin[ox].x, rm[ox].x);
        s_out[(2*tl+1)*25 + oy*5 + ox] = fmaxf(awin[ox].y, rm[ox].y);
        awin[ox] = rm[ox];
      }
    }
  }
  if (!sub){
    // after ph=5: awin = max(rm4, rm5) -> partial for oy2
    #pragma unroll
    for (int ox=0; ox<5; ++ox) s_part[tl][ox] = awin[ox];
  }
  __syncthreads();
  if (sub){
    // oy2 = max(max(rm4,rm5), rm6)
    #pragma unroll
    for (int ox=0; ox<5; ++ox){
      float2 p = s_part[tl][ox];
      s_out[(2*tl  )*25 + 2*5 + ox] = fmaxf(p.x, rm6s[ox].x);
      s_out[(2*tl+1)*25 + 2*5 + ox] = fmaxf(p.y, rm6s[ox].y);
    }
  }
  __syncthreads();

  // coalesced float4 store of this half's [256][5][5] chunk
  float4* dst = (float4*)(out + (size_t)r*(Cc*25) + half*(256*25));
  const float4* src = (const float4*)s_out;
  for (int k=t; k<(256*25)/4; k+=256) dst[k]=src[k];
}

// ---- fallback: NCHW fp32 direct (known-correct, used only if ws too small) ----
__global__ __launch_bounds__(512, 1)
void roi_align_max_nchw(const float* __restrict__ feat,
                        const float* __restrict__ rois,
                        float* __restrict__ out)
{
  __shared__ int   s_roff[AH][6];
  __shared__ float s_rw  [AH][6];
  __shared__ int   s_coff[AH][6];
  __shared__ float s_cw  [AH][6];
  __shared__ int   s_b;
  __shared__ __align__(16) float s_out[Cc*25];

  const int t = threadIdx.x;
  const int r = blockIdx.x;

  if (t < AH*6){
    ((float*)s_rw)[t] = 0.0f;  ((int*)s_roff)[t] = 0;
    ((float*)s_cw)[t] = 0.0f;  ((int*)s_coff)[t] = 0;
  }
  if (t == 0){
    int b = (int)rois[r*5+0];
    s_b = min(max(b, 0), Bn-1);
  }
  __syncthreads();

  if (t < AH || (t >= 64 && t < 64+AH)){
    const bool isrow = (t < AH);
    const int  p = isrow ? t : t-64;
    const float* rp = rois + r*5;
    const float c1 = rp[isrow?2:1], c2 = rp[isrow?4:3];
    float lo  = __fmul_rn(c1, 0.125f);
    float hi  = __fmul_rn(c2, 0.125f);
    float ext = fmaxf(__fsub_rn(hi,lo), 0.0f);
    float bin = __fdiv_rn(ext, 10.0f);
    float ctr = __fadd_rn(lo, __fmul_rn((float)p, bin));
    float strd = fmaxf(1.0f, rintf(__fdiv_rn(bin, 3.0f)));
    bool ok = (ctr >= 0.0f) && (ctr < 96.0f);
    int rws[6]; float wts[6]; int nv=0;
    #pragma unroll
    for (int s=0;s<3;++s){
      float cc = __fadd_rn(ctr, __fmul_rn((float)(s-1), strd));
      bool vv = (cc >= 0.0f) && (cc < 96.0f);
      float fl = fminf(fmaxf(floorf(cc),0.0f),94.0f);
      float fr = __fsub_rn(cc, fl);
      int ri = (int)fl;
      rws[2*s]=ri; rws[2*s+1]=ri+1;
      wts[2*s]  = vv ? __fsub_rn(1.0f,fr) : 0.0f;
      wts[2*s+1]= vv ? fr : 0.0f;
      nv += vv?1:0;
    }
    float sc = ok ? (1.0f/(float)nv) : 0.0f;
    int cr[6]; float cw[6]; int n=0;
    for (int k=0;k<6;++k){
      float wk=wts[k]; if (wk==0.0f) continue;
      if (n>0 && cr[n-1]==rws[k]) cw[n-1]+=wk;
      else { cr[n]=rws[k]; cw[n]=wk; ++n; }
    }
    const int mul = isrow ? Ww : 1;
    for (int k=0;k<n;++k){
      int off = cr[k]*mul;
      float wv = cw[k]*sc;
      if (isrow){ s_roff[p][k]=off; s_rw[p][k]=wv; }
      else      { s_coff[p][k]=off; s_cw[p][k]=wv; }
    }
  }
  __syncthreads();

  const float* f0 = feat + ((size_t)s_b*Cc + t)*HWc;
  float awin[5];
  for (int ph=0; ph<AH; ++ph){
    float binrow[AH];
    #pragma unroll
    for (int pw=0; pw<AH; ++pw){
      float acc = 0.0f;
      #pragma unroll
      for (int ai=0; ai<6; ++ai){
        float ra = s_rw[ph][ai];
        if (ra == 0.0f) continue;
        int ro = s_roff[ph][ai];
        #pragma unroll
        for (int bi=0; bi<6; ++bi){
          float cb = s_cw[pw][bi];
          if (cb == 0.0f) continue;
          acc = fmaf(ra*cb, f0[ro + s_coff[pw][bi]], acc);
        }
      }
      binrow[pw] = acc;
    }
    float rm[5];
    #pragma unroll
    for (int ox=0; ox<5; ++ox)
      rm[ox] = fmaxf(fmaxf(binrow[2*ox], binrow[2*ox+1]), binrow[2*ox+2]);
    if (ph == 0){
      #pragma unroll
      for (int ox=0; ox<5; ++ox) awin[ox] = rm[ox];
    } else if (ph & 1){
      #pragma unroll
      for (int ox=0; ox<5; ++ox) awin[ox] = fmaxf(awin[ox], rm[ox]);
    } else {
      int oy = (ph-2) >> 1;
      #pragma unroll
      for (int ox=0; ox<5; ++ox){
        s_out[t*25 + oy*5 + ox] = fmaxf(awin[ox], rm[ox]);
        awin[ox] = rm[ox];
      }
    }
  }
  __syncthreads();

  float4* dst = (float4*)(out + (size_t)r*(Cc*25));
  const float4* src = (const float4*)s_out;
  for (int k=t; k<(Cc*25)/4; k+=512) dst[k]=src[k];
}

extern "C" void kernel_launch(void* const* d_in, const int* in_sizes, int n_in,
                              void* d_out, int out_size, void* d_ws, size_t ws_size,
                              hipStream_t stream)
{
  (void)in_sizes; (void)n_in; (void)out_size;
  const float* feat = (const float*)d_in[0];
  const float* rois = (const float*)d_in[1];
  float* out = (float*)d_out;
  const size_t need = (size_t)Bn*HWc*Cc*sizeof(u16);   // 37.75 MB bf16 NHWC
  if (ws_size >= need){
    u32* ws = (u32*)d_ws;
    dim3 g(HWc/128, Cc/128, Bn);
    transpose_kernel<<<g, 256, 0, stream>>>(feat, ws);
    roi_align_max_nhwc<<<Rr*2, 256, 0, stream>>>(ws, rois, out);
  } else {
    roi_align_max_nchw<<<Rr, 512, 0, stream>>>(feat, rois, out);
  }
}

// Round 2
// 179.687 us; speedup vs baseline: 1.5154x; 1.5154x over previous
//
#include <hip/hip_runtime.h>
#include <stdint.h>

typedef unsigned short u16;
typedef unsigned int   u32;

#define Bn 4
#define Cc 512
#define Hh 96
#define Ww 96
#define HWc (Hh*Ww)   // 9216
#define AH 11
#define Rr 512
#define CP (Cc/2)     // 256 dwords per point (bf16 NHWC)

__device__ __forceinline__ u16 f2bf(float f){
  u32 u = __float_as_uint(f);
  u += 0x7fffu + ((u>>16)&1u);
  return (u16)(u>>16);
}
__device__ __forceinline__ u32 pk2(float a, float b){
  return (u32)f2bf(a) | ((u32)f2bf(b)<<16);
}

// ---- fp32 NCHW -> bf16-pair (u32) NHWC transpose; 128hw x 128c tile ----
// LDS: u32 tile[128*64], XOR-swizzled col' = cp ^ (hw>>2)  -> conflict-free
__global__ __launch_bounds__(256)
void transpose_kernel(const float* __restrict__ in, u32* __restrict__ out){
  __shared__ u32 tile[128*64];   // 32 KB
  const int t = threadIdx.x;
  const int hw0 = blockIdx.x*128, c0 = blockIdx.y*128, b = blockIdx.z;
  {
    const int q = t & 31, cp0 = t >> 5;           // q: hw quad, cp0: 0..7
    const float* ib = in + ((size_t)(b*Cc + c0))*HWc + hw0 + 4*q;
    #pragma unroll
    for (int p=0;p<8;++p){
      const int cp = cp0 + p*8;                   // 0..63 channel pair in tile
      const float* pa = ib + (size_t)(2*cp)*HWc;
      float4 A = *(const float4*)pa;
      float4 B = *(const float4*)(pa + HWc);
      const int cs = cp ^ q;                      // (4q+i)>>2 == q for i<4
      tile[(4*q+0)*64 + cs] = pk2(A.x,B.x);
      tile[(4*q+1)*64 + cs] = pk2(A.y,B.y);
      tile[(4*q+2)*64 + cs] = pk2(A.z,B.z);
      tile[(4*q+3)*64 + cs] = pk2(A.w,B.w);
    }
  }
  __syncthreads();
  {
    const int l = t & 63, wv = t >> 6;            // lane = cp, wave = row group
    u32* ob = out + ((size_t)b*HWc + hw0)*CP + (c0>>1) + l;
    #pragma unroll
    for (int k=0;k<32;++k){
      const int hw = wv*32 + k;
      ob[(size_t)hw*CP] = tile[hw*64 + (l ^ (hw>>2))];  // 256B contiguous store
    }
  }
}

// ---- fused RoIAlignAda + 3x3/s2 maxpool, NHWC bf16 ----
// grid 1024: r = bid>>1, half = bid&1; 256 threads (4 waves):
//   sub0 (t<128): ph rows 0..5, emits oy0,oy1, deposits max(rm4,rm5) in LDS
//   sub1 (t>=128): ph rows 6..10, emits oy3,oy4, then oy2 = max(part, rm6)
// NOTE: no min-waves arg in launch_bounds — (256,4) capped VGPR at 64 and
// spilled ~280 MB of scratch traffic (round-1 regression). Natural alloc
// ~100 VGPR gives 4 blocks/CU from the grid = 16 waves/CU.
__global__ __launch_bounds__(256)
void roi_align_max_nhwc(const u32* __restrict__ feat,
                        const float* __restrict__ rois,
                        float* __restrict__ out)
{
  __shared__ __align__(16) int4   s_ro[AH];
  __shared__ __align__(16) float4 s_rw[AH];
  __shared__ __align__(16) int4   s_co[AH];
  __shared__ __align__(16) float4 s_cw[AH];
  __shared__ int s_b;
  __shared__ __align__(16) float2 s_part[128][5];   // 5 KB: max(rm4,rm5)
  __shared__ __align__(16) float s_out[256*25];     // 25.6 KB

  const int t    = threadIdx.x;
  const int sub  = t >> 7;          // 0: rows 0..5, 1: rows 6..10
  const int tl   = t & 127;         // dword lane within half
  const int r    = blockIdx.x >> 1;
  const int half = blockIdx.x & 1;

  if (t == 0){
    int b = (int)rois[r*5+0];
    s_b = min(max(b, 0), Bn-1);
  }

  // geometry: threads 0..10 -> rows (ph), threads 64..74 -> cols (pw)
  if (t < AH || (t >= 64 && t < 64+AH)){
    const bool isrow = (t < AH);
    const int  p = isrow ? t : t-64;
    const float* rp = rois + r*5;
    const float c1 = rp[isrow?2:1], c2 = rp[isrow?4:3];
    // replicate np float32 ops exactly (no fp contraction at validity boundaries)
    float lo  = __fmul_rn(c1, 0.125f);
    float hi  = __fmul_rn(c2, 0.125f);
    float ext = fmaxf(__fsub_rn(hi,lo), 0.0f);
    float bin = __fdiv_rn(ext, 10.0f);
    float ctr = __fadd_rn(lo, __fmul_rn((float)p, bin));
    float strd = fmaxf(1.0f, rintf(__fdiv_rn(bin, 3.0f)));   // half-even == jnp.round
    bool ok = (ctr >= 0.0f) && (ctr < 96.0f);
    int rws[6]; float wts[6]; int nv=0;
    #pragma unroll
    for (int s=0;s<3;++s){
      float cc = __fadd_rn(ctr, __fmul_rn((float)(s-1), strd));
      bool vv = (cc >= 0.0f) && (cc < 96.0f);
      float fl = fminf(fmaxf(floorf(cc),0.0f),94.0f);
      float fr = __fsub_rn(cc, fl);
      int ri = (int)fl;
      rws[2*s]=ri; rws[2*s+1]=ri+1;
      wts[2*s]  = vv ? __fsub_rn(1.0f,fr) : 0.0f;
      wts[2*s+1]= vv ? fr : 0.0f;
      nv += vv?1:0;
    }
    float sc = ok ? (1.0f/(float)nv) : 0.0f;   // folds center_ok + 1/cnt (separable)
    // dedupe-merge (stride==1 here => <=4 unique), pad to 4 with w=0
    int cr[4]={0,0,0,0}; float cwv[4]={0.0f,0.0f,0.0f,0.0f}; int n=0;
    for (int k=0;k<6;++k){
      float wk=wts[k]; if (wk==0.0f) continue;
      int rr=rws[k]; bool fnd=false;
      for (int j=0;j<n;++j) if (cr[j]==rr){ cwv[j]+=wk; fnd=true; break; }
      if (!fnd && n<4){ cr[n]=rr; cwv[n]=wk; ++n; }
    }
    const int mul = isrow ? (Ww*CP) : CP;      // offsets in dwords
    if (isrow){
      s_ro[p] = make_int4(cr[0]*mul, cr[1]*mul, cr[2]*mul, cr[3]*mul);
      s_rw[p] = make_float4(cwv[0]*sc, cwv[1]*sc, cwv[2]*sc, cwv[3]*sc);
    } else {
      s_co[p] = make_int4(cr[0]*mul, cr[1]*mul, cr[2]*mul, cr[3]*mul);
      s_cw[p] = make_float4(cwv[0]*sc, cwv[1]*sc, cwv[2]*sc, cwv[3]*sc);
    }
  }
  __syncthreads();

  const u32* fbase = feat + (size_t)s_b*((size_t)HWc*CP);
  const int tb = half*128 + tl;                // this thread's dword lane

  // hoist column voffsets (BYTE offsets: bare saddr+voffset loads) + weights
  int   vo[AH][4]; float cwr[AH][4];
  #pragma unroll
  for (int pw=0; pw<AH; ++pw){
    int4 c4 = s_co[pw]; float4 w4 = s_cw[pw];
    vo[pw][0]=(tb+c4.x)*4; vo[pw][1]=(tb+c4.y)*4; vo[pw][2]=(tb+c4.z)*4; vo[pw][3]=(tb+c4.w)*4;
    cwr[pw][0]=w4.x; cwr[pw][1]=w4.y; cwr[pw][2]=w4.z; cwr[pw][3]=w4.w;
  }

  float2 awin[5], rm6s[5];
  const int ph0 = sub ? 6 : 0;
  const int phN = sub ? 10 : 5;
  #pragma unroll 1
  for (int ph=ph0; ph<=phN; ++ph){
    int4   r4 = s_ro[ph];
    float4 w4 = s_rw[ph];
    // scalar row bases (SGPR-pair addressing for the gathers)
    const char* r0 = (const char*)(fbase + __builtin_amdgcn_readfirstlane(r4.x));
    const char* r1 = (const char*)(fbase + __builtin_amdgcn_readfirstlane(r4.y));
    const char* r2 = (const char*)(fbase + __builtin_amdgcn_readfirstlane(r4.z));
    const char* r3 = (const char*)(fbase + __builtin_amdgcn_readfirstlane(r4.w));
    const float rw_[4] = {w4.x, w4.y, w4.z, w4.w};
    float2 binr[AH];
    #pragma unroll
    for (int pw=0; pw<AH; ++pw){
      u32 v[16];
      #pragma unroll
      for (int j=0;j<4;++j){
        v[0*4+j] = *(const u32*)(r0 + vo[pw][j]);
        v[1*4+j] = *(const u32*)(r1 + vo[pw][j]);
        v[2*4+j] = *(const u32*)(r2 + vo[pw][j]);
        v[3*4+j] = *(const u32*)(r3 + vo[pw][j]);
      }
      // separable: column-combine per row, then row-combine (no weight muls)
      float ax=0.0f, ay=0.0f;
      #pragma unroll
      for (int i=0;i<4;++i){
        float cx=0.0f, cy=0.0f;
        #pragma unroll
        for (int j=0;j<4;++j){
          u32 d = v[i*4+j];
          cx = fmaf(cwr[pw][j], __uint_as_float(d<<16),           cx);
          cy = fmaf(cwr[pw][j], __uint_as_float(d & 0xffff0000u), cy);
        }
        ax = fmaf(rw_[i], cx, ax);
        ay = fmaf(rw_[i], cy, ay);
      }
      binr[pw] = make_float2(ax, ay);
    }
    float2 rm[5];
    #pragma unroll
    for (int ox=0; ox<5; ++ox){
      rm[ox].x = fmaxf(fmaxf(binr[2*ox].x, binr[2*ox+1].x), binr[2*ox+2].x);
      rm[ox].y = fmaxf(fmaxf(binr[2*ox].y, binr[2*ox+1].y), binr[2*ox+2].y);
    }
    if (ph == ph0){
      #pragma unroll
      for (int ox=0; ox<5; ++ox){
        awin[ox] = rm[ox];
        if (sub) rm6s[ox] = rm[ox];    // keep rm6 for the straddling oy2 window
      }
    } else if (ph & 1){
      #pragma unroll
      for (int ox=0; ox<5; ++ox){
        awin[ox].x = fmaxf(awin[ox].x, rm[ox].x);
        awin[ox].y = fmaxf(awin[ox].y, rm[ox].y);
      }
    } else {
      const int oy = (ph-2) >> 1;      // sub0: 0,1   sub1: 3,4
      #pragma unroll
      for (int ox=0; ox<5; ++ox){
        s_out[(2*tl  )*25 + oy*5 + ox] = fmaxf(awin[ox].x, rm[ox].x);
        s_out[(2*tl+1)*25 + oy*5 + ox] = fmaxf(awin[ox].y, rm[ox].y);
        awin[ox] = rm[ox];
      }
    }
  }
  if (!sub){
    // after ph=5: awin = max(rm4, rm5) -> partial for oy2
    #pragma unroll
    for (int ox=0; ox<5; ++ox) s_part[tl][ox] = awin[ox];
  }
  __syncthreads();
  if (sub){
    // oy2 = max(max(rm4,rm5), rm6)
    #pragma unroll
    for (int ox=0; ox<5; ++ox){
      float2 p = s_part[tl][ox];
      s_out[(2*tl  )*25 + 2*5 + ox] = fmaxf(p.x, rm6s[ox].x);
      s_out[(2*tl+1)*25 + 2*5 + ox] = fmaxf(p.y, rm6s[ox].y);
    }
  }
  __syncthreads();

  // coalesced float4 store of this half's [256][5][5] chunk
  float4* dst = (float4*)(out + (size_t)r*(Cc*25) + half*(256*25));
  const float4* src = (const float4*)s_out;
  for (int k=t; k<(256*25)/4; k+=256) dst[k]=src[k];
}

// ---- fallback: NCHW fp32 direct (known-correct, used only if ws too small) ----
__global__ __launch_bounds__(512, 1)
void roi_align_max_nchw(const float* __restrict__ feat,
                        const float* __restrict__ rois,
                        float* __restrict__ out)
{
  __shared__ int   s_roff[AH][6];
  __shared__ float s_rw  [AH][6];
  __shared__ int   s_coff[AH][6];
  __shared__ float s_cw  [AH][6];
  __shared__ int   s_b;
  __shared__ __align__(16) float s_out[Cc*25];

  const int t = threadIdx.x;
  const int r = blockIdx.x;

  if (t < AH*6){
    ((float*)s_rw)[t] = 0.0f;  ((int*)s_roff)[t] = 0;
    ((float*)s_cw)[t] = 0.0f;  ((int*)s_coff)[t] = 0;
  }
  if (t == 0){
    int b = (int)rois[r*5+0];
    s_b = min(max(b, 0), Bn-1);
  }
  __syncthreads();

  if (t < AH || (t >= 64 && t < 64+AH)){
    const bool isrow = (t < AH);
    const int  p = isrow ? t : t-64;
    const float* rp = rois + r*5;
    const float c1 = rp[isrow?2:1], c2 = rp[isrow?4:3];
    float lo  = __fmul_rn(c1, 0.125f);
    float hi  = __fmul_rn(c2, 0.125f);
    float ext = fmaxf(__fsub_rn(hi,lo), 0.0f);
    float bin = __fdiv_rn(ext, 10.0f);
    float ctr = __fadd_rn(lo, __fmul_rn((float)p, bin));
    float strd = fmaxf(1.0f, rintf(__fdiv_rn(bin, 3.0f)));
    bool ok = (ctr >= 0.0f) && (ctr < 96.0f);
    int rws[6]; float wts[6]; int nv=0;
    #pragma unroll
    for (int s=0;s<3;++s){
      float cc = __fadd_rn(ctr, __fmul_rn((float)(s-1), strd));
      bool vv = (cc >= 0.0f) && (cc < 96.0f);
      float fl = fminf(fmaxf(floorf(cc),0.0f),94.0f);
      float fr = __fsub_rn(cc, fl);
      int ri = (int)fl;
      rws[2*s]=ri; rws[2*s+1]=ri+1;
      wts[2*s]  = vv ? __fsub_rn(1.0f,fr) : 0.0f;
      wts[2*s+1]= vv ? fr : 0.0f;
      nv += vv?1:0;
    }
    float sc = ok ? (1.0f/(float)nv) : 0.0f;
    int cr[6]; float cw[6]; int n=0;
    for (int k=0;k<6;++k){
      float wk=wts[k]; if (wk==0.0f) continue;
      if (n>0 && cr[n-1]==rws[k]) cw[n-1]+=wk;
      else { cr[n]=rws[k]; cw[n]=wk; ++n; }
    }
    const int mul = isrow ? Ww : 1;
    for (int k=0;k<n;++k){
      int off = cr[k]*mul;
      float wv = cw[k]*sc;
      if (isrow){ s_roff[p][k]=off; s_rw[p][k]=wv; }
      else      { s_coff[p][k]=off; s_cw[p][k]=wv; }
    }
  }
  __syncthreads();

  const float* f0 = feat + ((size_t)s_b*Cc + t)*HWc;
  float awin[5];
  for (int ph=0; ph<AH; ++ph){
    float binrow[AH];
    #pragma unroll
    for (int pw=0; pw<AH; ++pw){
      float acc = 0.0f;
      #pragma unroll
      for (int ai=0; ai<6; ++ai){
        float ra = s_rw[ph][ai];
        if (ra == 0.0f) continue;
        int ro = s_roff[ph][ai];
        #pragma unroll
        for (int bi=0; bi<6; ++bi){
          float cb = s_cw[pw][bi];
          if (cb == 0.0f) continue;
          acc = fmaf(ra*cb, f0[ro + s_coff[pw][bi]], acc);
        }
      }
      binrow[pw] = acc;
    }
    float rm[5];
    #pragma unroll
    for (int ox=0; ox<5; ++ox)
      rm[ox] = fmaxf(fmaxf(binrow[2*ox], binrow[2*ox+1]), binrow[2*ox+2]);
    if (ph == 0){
      #pragma unroll
      for (int ox=0; ox<5; ++ox) awin[ox] = rm[ox];
    } else if (ph & 1){
      #pragma unroll
      for (int ox=0; ox<5; ++ox) awin[ox] = fmaxf(awin[ox], rm[ox]);
    } else {
      int oy = (ph-2) >> 1;
      #pragma unroll
      for (int ox=0; ox<5; ++ox){
        s_out[t*25 + oy*5 + ox] = fmaxf(awin[ox], rm[ox]);
        awin[ox] = rm[ox];
      }
    }
  }
  __syncthreads();

  float4* dst = (float4*)(out + (size_t)r*(Cc*25));
  const float4* src = (const float4*)s_out;
  for (int k=t; k<(Cc*25)/4; k+=512) dst[k]=src[k];
}

extern "C" void kernel_launch(void* const* d_in, const int* in_sizes, int n_in,
                              void* d_out, int out_size, void* d_ws, size_t ws_size,
                              hipStream_t stream)
{
  (void)in_sizes; (void)n_in; (void)out_size;
  const float* feat = (const float*)d_in[0];
  const float* rois = (const float*)d_in[1];
  float* out = (float*)d_out;
  const size_t need = (size_t)Bn*HWc*Cc*sizeof(u16);   // 37.75 MB bf16 NHWC
  if (ws_size >= need){
    u32* ws = (u32*)d_ws;
    dim3 g(HWc/128, Cc/128, Bn);
    transpose_kernel<<<g, 256, 0, stream>>>(feat, ws);
    roi_align_max_nhwc<<<Rr*2, 256, 0, stream>>>(ws, rois, out);
  } else {
    roi_align_max_nchw<<<Rr, 512, 0, stream>>>(feat, rois, out);
  }
}